// Round 14
// baseline (125.120 us; speedup 1.0000x reference)
//
#include <hip/hip_runtime.h>
#include <math.h>

#define NN 768
#define CC 256
#define TI 3     // rows per k_prep block / per k_attn wave
#define NJC 12   // j chunks of 64: 12 * 64 = 768

__device__ __forceinline__ float leaky(float x) { return x >= 0.0f ? x : 0.2f * x; }

__device__ __forceinline__ float rl(float v, int l) {   // wave broadcast, VALU pipe
    return __uint_as_float(__builtin_amdgcn_readlane(__float_as_uint(v), l));
}

__device__ __forceinline__ float waveMax(float v) {
    #pragma unroll
    for (int o = 32; o > 0; o >>= 1) v = fmaxf(v, __shfl_xor(v, o, 64));
    return v;
}
__device__ __forceinline__ float waveSum(float v) {
    #pragma unroll
    for (int o = 32; o > 0; o >>= 1) v += __shfl_xor(v, o, 64);
    return v;
}

__device__ __forceinline__ void fma4(float4& h, float e, const float4& fv) {
    h.x = fmaf(e, fv.x, h.x);
    h.y = fmaf(e, fv.y, h.y);
    h.z = fmaf(e, fv.z, h.z);
    h.w = fmaf(e, fv.w, h.w);
}

// Kernel 1 (unchanged): f = features @ FC; g[c][j] = w1*f[j][c]+b;
// D0/D1 = per-row linear-term dots; ut4[triple][c] = {w0*f_r0[c], w0*f_r1[c],
// w0*f_r2[c], 0.4*lin_w[c]}.
__global__ __launch_bounds__(768) void k_prep(
    const float* __restrict__ features,
    const float* __restrict__ FC,
    const float* __restrict__ fc_w,
    const float* __restrict__ fc_b,
    const float* __restrict__ lin_w,
    float* __restrict__ f,
    float* __restrict__ g,
    float* __restrict__ D0,
    float* __restrict__ D1,
    float4* __restrict__ ut4)
{
    __shared__ float sA[TI * CC];
    __shared__ float sF[TI * CC];
    __shared__ float sredD[12], sredW[12];

    const int t  = threadIdx.x;
    const int r  = t >> 8;
    const int c  = t & 255;
    const int i0 = blockIdx.x * TI;

    sA[r * CC + c] = features[(i0 + r) * CC + c];
    __syncthreads();

    float a = 0.f;
    const float* fcp = FC + c;
    const float* ap  = sA + r * CC;
    #pragma unroll 8
    for (int k = 0; k < CC; ++k)
        a = fmaf(ap[k], fcp[k * CC], a);

    const float w1 = fc_w[1], b = fc_b[0];
    f[(i0 + r) * CC + c] = a;
    g[c * NN + i0 + r]   = fmaf(w1, a, b);
    sF[r * CC + c] = a;

    const float lw = lin_w[c];
    float dv = waveSum(lw * a);
    float wv = waveSum(lw);
    const int wid = t >> 6;
    if ((t & 63) == 0) { sredD[wid] = dv; sredW[wid] = wv; }
    __syncthreads();
    if (t < TI) {
        float D = sredD[t*4] + sredD[t*4+1] + sredD[t*4+2] + sredD[t*4+3];
        float W = sredW[t*4] + sredW[t*4+1] + sredW[t*4+2] + sredW[t*4+3];
        D0[i0 + t] = fc_w[0] * D;
        D1[i0 + t] = fmaf(w1, D, b * W);
    }
    if (t < CC) {
        const float w0 = fc_w[0];
        ut4[blockIdx.x * CC + t] = make_float4(w0 * sF[t],
                                               w0 * sF[CC + t],
                                               w0 * sF[2*CC + t],
                                               0.4f * lin_w[t]);
    }
}

// Kernel 2: WAVE-AUTONOMOUS. 768 blocks x 256 threads, but each of the 3072
// waves owns a full task (row-triple rg x 64-j chunk jc) end-to-end: scores,
// wave-internal softmax (shfl), h-partial, store. ZERO __syncthreads, ZERO
// LDS — the barrier-phase lockstep drains were the last uneliminated
// invariant of rounds 2-13. Broadcasts via v_readlane from own registers.
__global__ __launch_bounds__(256) void k_attn(
    const float* __restrict__ f,      // [N][C]
    const float* __restrict__ g,      // [C][N]
    const float4* __restrict__ ut4,   // [N/3][C]
    const float* __restrict__ D0,     // [N]
    const float* __restrict__ D1,     // [N]
    const float* __restrict__ coords, // [N][3]
    const float* __restrict__ sc_w,
    const float* __restrict__ sc_b,
    const float* __restrict__ lin_w,  // [C+3]
    const float* __restrict__ lin_b,
    float* __restrict__ hp,           // [NJC][N][C] partial sums
    float* __restrict__ Mp,           // [N][NJC] partial max
    float* __restrict__ Lp)           // [N][NJC] partial expsum
{
    const int t    = threadIdx.x;
    const int w    = t >> 6;
    const int lane = t & 63;
    const int rg   = blockIdx.x / 3;          // row-triple 0..255 (shared by block's 4 waves)
    const int jc   = (blockIdx.x % 3) * 4 + w; // j-chunk 0..11
    const int i0   = rg * TI;
    const int jb   = jc << 6;
    const int j    = jb + lane;                // this lane's j

    // wave's u-operand: lane holds quads for c = lane, 64+lane, 128+lane, 192+lane
    float4 uq0 = ut4[(size_t)rg * CC +        lane];
    float4 uq1 = ut4[(size_t)rg * CC +  64 + lane];
    float4 uq2 = ut4[(size_t)rg * CC + 128 + lane];
    float4 uq3 = ut4[(size_t)rg * CC + 192 + lane];

    // ---- Phase A: s_r = sum_c 0.4*wc*|u_rc + g_cj| for own j, 3 rows ----
    float a0 = 0.f, a1 = 0.f, a2 = 0.f;
    const float* gp = g + j;
    #pragma unroll
    for (int k = 0; k < 4; ++k) {
        float4 uq = (k == 0) ? uq0 : (k == 1) ? uq1 : (k == 2) ? uq2 : uq3;
        const float* gk = gp + (size_t)(k << 6) * NN;
        #pragma unroll 8
        for (int li = 0; li < 64; ++li) {
            float gv = gk[li * NN];        // coalesced 256B/wave, L2
            float w4 = rl(uq.w, li);       // VALU broadcasts from own regs
            float u0 = rl(uq.x, li);
            float u1 = rl(uq.y, li);
            float u2 = rl(uq.z, li);
            a0 = fmaf(w4, fabsf(u0 + gv), a0);
            a1 = fmaf(w4, fabsf(u1 + gv), a1);
            a2 = fmaf(w4, fabsf(u2 + gv), a2);
        }
    }

    // coord part + 0.6-linear part + outer leaky
    const float sw0 = sc_w[0], sw1 = sc_w[1], sb = sc_b[0], lb = lin_b[0];
    const float lw30 = lin_w[CC], lw31 = lin_w[CC+1], lw32 = lin_w[CC+2];
    const float cj0 = fmaf(sw1, coords[j*3+0], sb);
    const float cj1 = fmaf(sw1, coords[j*3+1], sb);
    const float cj2 = fmaf(sw1, coords[j*3+2], sb);
    const float d1  = D1[j];
    float accs[3] = {a0, a1, a2};
    float scv[3];
    #pragma unroll
    for (int rr = 0; rr < TI; ++rr) {
        const int i = i0 + rr;
        float sd = lw30 * leaky(fmaf(sw0, coords[i*3+0], cj0))
                 + lw31 * leaky(fmaf(sw0, coords[i*3+1], cj1))
                 + lw32 * leaky(fmaf(sw0, coords[i*3+2], cj2));
        scv[rr] = leaky(accs[rr] + sd + 0.6f * (D0[i] + d1) + lb);
    }

    // ---- Wave-internal partial softmax over this chunk's 64 j ----
    float m0 = waveMax(scv[0]);
    float m1 = waveMax(scv[1]);
    float m2 = waveMax(scv[2]);
    float e0 = __expf(scv[0] - m0);
    float e1 = __expf(scv[1] - m1);
    float e2 = __expf(scv[2] - m2);
    float l0 = waveSum(e0);
    float l1 = waveSum(e1);
    float l2 = waveSum(e2);
    if (lane == 0) {
        Mp[(i0+0) * NJC + jc] = m0;  Lp[(i0+0) * NJC + jc] = l0;
        Mp[(i0+1) * NJC + jc] = m1;  Lp[(i0+1) * NJC + jc] = l1;
        Mp[(i0+2) * NJC + jc] = m2;  Lp[(i0+2) * NJC + jc] = l2;
    }

    // ---- Phase B: h_r[c] = sum_{jx in chunk} e_r,jx * f_jx[c]; lane owns c-quad ----
    float4 h0 = make_float4(0.f,0.f,0.f,0.f);
    float4 h1 = h0, h2 = h0;
    const float4* f4 = (const float4*)f + (size_t)jb * 64 + lane;  // [N][64] float4
    #pragma unroll 8
    for (int jx = 0; jx < 64; ++jx) {
        float4 fv = f4[jx * 64];          // coalesced 1KB/wave
        float se0 = rl(e0, jx);           // e lives in this wave's own lanes
        float se1 = rl(e1, jx);
        float se2 = rl(e2, jx);
        fma4(h0, se0, fv);
        fma4(h1, se1, fv);
        fma4(h2, se2, fv);
    }
    float4* hpp = (float4*)(hp + ((size_t)jc * NN + i0) * CC) + lane;
    hpp[0]      = h0;                      // row i0   : coalesced float4
    hpp[64]     = h1;                      // row i0+1
    hpp[128]    = h2;                      // row i0+2
}

// Kernel 3: combine the 12 j-chunk partials per row, normalize, elu.
__global__ __launch_bounds__(256) void k_comb(
    const float* __restrict__ hp,
    const float* __restrict__ Mp,
    const float* __restrict__ Lp,
    float* __restrict__ out)
{
    const int t = threadIdx.x;
    const int i = blockIdx.x;

    float mv[NJC];
    #pragma unroll
    for (int k = 0; k < NJC; ++k) mv[k] = Mp[i*NJC + k];
    float M = mv[0];
    #pragma unroll
    for (int k = 1; k < NJC; ++k) M = fmaxf(M, mv[k]);
    float wk[NJC], den = 0.f;
    #pragma unroll
    for (int k = 0; k < NJC; ++k) {
        wk[k] = __expf(mv[k] - M);
        den = fmaf(wk[k], Lp[i*NJC + k], den);
    }
    float inv = 1.0f / den;

    float num = 0.f;
    #pragma unroll
    for (int k = 0; k < NJC; ++k)
        num = fmaf(wk[k], hp[((size_t)k*NN + i)*CC + t], num);
    float v = num * inv;
    out[i*CC + t] = (v > 0.f) ? v : (__expf(v) - 1.0f);
}

extern "C" void kernel_launch(void* const* d_in, const int* in_sizes, int n_in,
                              void* d_out, int out_size, void* d_ws, size_t ws_size,
                              hipStream_t stream) {
    const float* features = (const float*)d_in[0];
    const float* coords   = (const float*)d_in[1];
    // d_in[2] = adj, unused by forward
    const float* FC       = (const float*)d_in[3];
    const float* fc_w     = (const float*)d_in[4];
    const float* fc_b     = (const float*)d_in[5];
    const float* sc_w     = (const float*)d_in[6];
    const float* sc_b     = (const float*)d_in[7];
    const float* lin_w    = (const float*)d_in[8];
    const float* lin_b    = (const float*)d_in[9];
    float* out = (float*)d_out;

    float* f  = (float*)d_ws;              // N*C
    float* g  = f  + NN*CC;                // C*N
    float* D0 = g  + CC*NN;                // N
    float* D1 = D0 + NN;                   // N
    float* Mp = D1 + NN;                   // N*NJC
    float* Lp = Mp + NN*NJC;               // N*NJC
    float* hp = Lp + NN*NJC;               // NJC*N*C (~9.4 MB)
    float4* ut4;
    {
        size_t off = (size_t)((char*)(hp + (size_t)NJC*NN*CC) - (char*)d_ws);
        off = (off + 15) & ~(size_t)15;
        ut4 = (float4*)((char*)d_ws + off); // (N/3)*C float4, 16B-aligned
    }

    k_prep<<<NN/TI, 768, 0, stream>>>(features, FC, fc_w, fc_b, lin_w, f, g, D0, D1, ut4);
    k_attn<<<(NN/TI)*3, 256, 0, stream>>>(f, g, ut4, D0, D1, coords, sc_w, sc_b,
                                          lin_w, lin_b, hp, Mp, Lp);
    k_comb<<<NN, 256, 0, stream>>>(hp, Mp, Lp, out);
}

// Round 15
// 111.559 us; speedup vs baseline: 1.1216x; 1.1216x over previous
//
#include <hip/hip_runtime.h>
#include <math.h>

#define NN 768
#define CC 256
#define TI 3     // rows per block (both kernels)
#define JC 256   // j columns per k_attn block
#define NJC 3    // j chunks: 3 * 256 = 768

__device__ __forceinline__ float leaky(float x) { return x >= 0.0f ? x : 0.2f * x; }

__device__ __forceinline__ float waveMax(float v) {
    #pragma unroll
    for (int o = 32; o > 0; o >>= 1) v = fmaxf(v, __shfl_xor(v, o, 64));
    return v;
}
__device__ __forceinline__ float waveSum(float v) {
    #pragma unroll
    for (int o = 32; o > 0; o >>= 1) v += __shfl_xor(v, o, 64);
    return v;
}

// Kernel 1: f = features @ FC; g[c][j] = w1*f[j][c]+b (transposed);
// D0/D1 = per-row linear-term dots; ut4[triple][c] = {w0*f_r0[c], w0*f_r1[c],
// w0*f_r2[c], 0.4*lin_w[c]}.
__global__ __launch_bounds__(768) void k_prep(
    const float* __restrict__ features,
    const float* __restrict__ FC,
    const float* __restrict__ fc_w,
    const float* __restrict__ fc_b,
    const float* __restrict__ lin_w,
    float* __restrict__ f,
    float* __restrict__ g,
    float* __restrict__ D0,
    float* __restrict__ D1,
    float4* __restrict__ ut4)
{
    __shared__ float sA[TI * CC];
    __shared__ float sF[TI * CC];
    __shared__ float sredD[12], sredW[12];

    const int t  = threadIdx.x;
    const int r  = t >> 8;
    const int c  = t & 255;
    const int i0 = blockIdx.x * TI;

    sA[r * CC + c] = features[(i0 + r) * CC + c];
    __syncthreads();

    float a = 0.f;
    const float* fcp = FC + c;
    const float* ap  = sA + r * CC;
    #pragma unroll 8
    for (int k = 0; k < CC; ++k)
        a = fmaf(ap[k], fcp[k * CC], a);

    const float w1 = fc_w[1], b = fc_b[0];
    f[(i0 + r) * CC + c] = a;
    g[c * NN + i0 + r]   = fmaf(w1, a, b);
    sF[r * CC + c] = a;

    const float lw = lin_w[c];
    float dv = waveSum(lw * a);
    float wv = waveSum(lw);
    const int wid = t >> 6;
    if ((t & 63) == 0) { sredD[wid] = dv; sredW[wid] = wv; }
    __syncthreads();
    if (t < TI) {
        float D = sredD[t*4] + sredD[t*4+1] + sredD[t*4+2] + sredD[t*4+3];
        float W = sredW[t*4] + sredW[t*4+1] + sredW[t*4+2] + sredW[t*4+3];
        D0[i0 + t] = fc_w[0] * D;
        D1[i0 + t] = fmaf(w1, D, b * W);
    }
    if (t < CC) {
        const float w0 = fc_w[0];
        ut4[blockIdx.x * CC + t] = make_float4(w0 * sF[t],
                                               w0 * sF[CC + t],
                                               w0 * sF[2*CC + t],
                                               0.4f * lin_w[t]);
    }
}

// Kernel 2 (round-10 champion): 768 blocks x 256 threads, block = (row-triple
// it, j-chunk jc). Phase 1: lane owns a j-quad (float4 g loads, 96 KB in
// flight); wave owns a 64-c slice; u via 4 KB LDS stage + ds_read_b128
// broadcast. Phase 3: wave owns j-slice, lane owns c-quad, pp via b128
// broadcast. Best measured variant of nine structural alternatives.
__global__ __launch_bounds__(256) void k_attn(
    const float* __restrict__ f,      // [N][C]
    const float* __restrict__ g,      // [C][N]
    const float4* __restrict__ ut4,   // [N/3][C]
    const float* __restrict__ D0,     // [N]
    const float* __restrict__ D1,     // [N]
    const float* __restrict__ coords, // [N][3]
    const float* __restrict__ sc_w,
    const float* __restrict__ sc_b,
    const float* __restrict__ lin_w,  // [C+3]
    const float* __restrict__ lin_b,
    float* __restrict__ hp,           // [NJC][N][C] partial sums
    float* __restrict__ Mp,           // [N][NJC] partial max
    float* __restrict__ Lp)           // [N][NJC] partial expsum
{
    __shared__ float4 su4[CC];          // 4 KB: staged u for this row-triple
    __shared__ float  spart[4][TI][JC]; // 12 KB: per-c-slice score partials
    __shared__ float4 pp[JC];           // 4 KB: {e0,e1,e2,-} per block-local j
    __shared__ float  hpart[4][TI][CC]; // 12 KB: per-wave h partials
    __shared__ float4 sredm4[4];
    __shared__ float4 sreds4[4];

    const int t    = threadIdx.x;
    const int it   = blockIdx.x & 255;  // row-triple
    const int jc   = blockIdx.x >> 8;   // j-chunk 0..2
    const int i0   = it * TI;
    const int jb   = jc * JC;
    const int j    = jb + t;
    const int w    = t >> 6;
    const int lane = t & 63;

    // stage u into LDS (one coalesced 4 KB read per block)
    su4[t] = ut4[(size_t)it * CC + t];
    __syncthreads();

    // ---- Phase 1: acc[rr] over c-slice [64w,64w+64) for j-quad jb+4*lane ----
    float4 a0 = make_float4(0.f,0.f,0.f,0.f);
    float4 a1 = a0, a2 = a0;
    const float4* gq = (const float4*)g + (size_t)(w << 6) * (NN/4) + (jb >> 2) + lane;
    const float4* su = su4 + (w << 6);
    #pragma unroll 8
    for (int cc = 0; cc < 64; ++cc) {
        float4 gv = gq[cc * (NN/4)];   // coalesced 1KB/wave, L2
        float4 u  = su[cc];            // ds_read_b128 broadcast (conflict-free)
        a0.x = fmaf(u.w, fabsf(u.x + gv.x), a0.x);
        a0.y = fmaf(u.w, fabsf(u.x + gv.y), a0.y);
        a0.z = fmaf(u.w, fabsf(u.x + gv.z), a0.z);
        a0.w = fmaf(u.w, fabsf(u.x + gv.w), a0.w);
        a1.x = fmaf(u.w, fabsf(u.y + gv.x), a1.x);
        a1.y = fmaf(u.w, fabsf(u.y + gv.y), a1.y);
        a1.z = fmaf(u.w, fabsf(u.y + gv.z), a1.z);
        a1.w = fmaf(u.w, fabsf(u.y + gv.w), a1.w);
        a2.x = fmaf(u.w, fabsf(u.z + gv.x), a2.x);
        a2.y = fmaf(u.w, fabsf(u.z + gv.y), a2.y);
        a2.z = fmaf(u.w, fabsf(u.z + gv.z), a2.z);
        a2.w = fmaf(u.w, fabsf(u.z + gv.w), a2.w);
    }
    *(float4*)&spart[w][0][4*lane] = a0;
    *(float4*)&spart[w][1][4*lane] = a1;
    *(float4*)&spart[w][2][4*lane] = a2;
    __syncthreads();

    // ---- Tail: thread t owns j = jb + t ----
    float accs[3];
    #pragma unroll
    for (int rr = 0; rr < TI; ++rr)
        accs[rr] = spart[0][rr][t] + spart[1][rr][t]
                 + spart[2][rr][t] + spart[3][rr][t];

    const float sw0 = sc_w[0], sw1 = sc_w[1], sb = sc_b[0], lb = lin_b[0];
    const float lw30 = lin_w[CC], lw31 = lin_w[CC+1], lw32 = lin_w[CC+2];
    const float cj0 = fmaf(sw1, coords[j*3+0], sb);
    const float cj1 = fmaf(sw1, coords[j*3+1], sb);
    const float cj2 = fmaf(sw1, coords[j*3+2], sb);
    const float d1  = D1[j];
    float scv[3];
    #pragma unroll
    for (int rr = 0; rr < TI; ++rr) {
        const int i = i0 + rr;
        float sd = lw30 * leaky(fmaf(sw0, coords[i*3+0], cj0))
                 + lw31 * leaky(fmaf(sw0, coords[i*3+1], cj1))
                 + lw32 * leaky(fmaf(sw0, coords[i*3+2], cj2));
        scv[rr] = leaky(accs[rr] + sd + 0.6f * (D0[i] + d1) + lb);
    }

    // ---- Phase 2: partial softmax over this block's 256 j ----
    {
        float v0 = waveMax(scv[0]);
        float v1 = waveMax(scv[1]);
        float v2 = waveMax(scv[2]);
        if (lane == 0) sredm4[w] = make_float4(v0, v1, v2, 0.f);
    }
    __syncthreads();
    float m[TI];
    {
        float4 x0 = sredm4[0], x1 = sredm4[1], x2 = sredm4[2], x3 = sredm4[3];
        m[0] = fmaxf(fmaxf(x0.x, x1.x), fmaxf(x2.x, x3.x));
        m[1] = fmaxf(fmaxf(x0.y, x1.y), fmaxf(x2.y, x3.y));
        m[2] = fmaxf(fmaxf(x0.z, x1.z), fmaxf(x2.z, x3.z));
    }
    float e0 = __expf(scv[0] - m[0]);
    float e1 = __expf(scv[1] - m[1]);
    float e2 = __expf(scv[2] - m[2]);
    pp[t] = make_float4(e0, e1, e2, 0.f);
    {
        float v0 = waveSum(e0);
        float v1 = waveSum(e1);
        float v2 = waveSum(e2);
        if (lane == 0) sreds4[w] = make_float4(v0, v1, v2, 0.f);
    }
    __syncthreads();   // publishes pp + sreds4
    if (t < TI) {
        float4 s0 = sreds4[0], s1 = sreds4[1], s2 = sreds4[2], s3 = sreds4[3];
        float l = (t == 0) ? (s0.x + s1.x + s2.x + s3.x)
                : (t == 1) ? (s0.y + s1.y + s2.y + s3.y)
                           : (s0.z + s1.z + s2.z + s3.z);
        float mm = (t == 0) ? m[0] : (t == 1) ? m[1] : m[2];
        Mp[(i0 + t) * NJC + jc] = mm;
        Lp[(i0 + t) * NJC + jc] = l;
    }

    // ---- Phase 3: wave w owns j-slice [64w,64w+64); lane owns 4 channels ----
    float4 h0 = make_float4(0.f,0.f,0.f,0.f);
    float4 h1 = h0, h2 = h0;
    const float4* f4 = (const float4*)f;   // [N][64] float4
    const int jsl = w * 64;
    #pragma unroll 4
    for (int jx = 0; jx < 64; ++jx) {
        const int jl = jsl + jx;
        float4 fv = f4[(size_t)(jb + jl) * 64 + lane];  // coalesced 1KB/wave
        float4 e  = pp[jl];                              // ds_read_b128 broadcast
        h0.x = fmaf(e.x, fv.x, h0.x); h0.y = fmaf(e.x, fv.y, h0.y);
        h0.z = fmaf(e.x, fv.z, h0.z); h0.w = fmaf(e.x, fv.w, h0.w);
        h1.x = fmaf(e.y, fv.x, h1.x); h1.y = fmaf(e.y, fv.y, h1.y);
        h1.z = fmaf(e.y, fv.z, h1.z); h1.w = fmaf(e.y, fv.w, h1.w);
        h2.x = fmaf(e.z, fv.x, h2.x); h2.y = fmaf(e.z, fv.y, h2.y);
        h2.z = fmaf(e.z, fv.z, h2.z); h2.w = fmaf(e.z, fv.w, h2.w);
    }
    *(float4*)&hpart[w][0][4*lane] = h0;
    *(float4*)&hpart[w][1][4*lane] = h1;
    *(float4*)&hpart[w][2][4*lane] = h2;
    __syncthreads();

    // ---- Reduce the 4 wave-partials per row; store hp ----
    #pragma unroll
    for (int r = 0; r < TI; ++r) {
        float h = hpart[0][r][t] + hpart[1][r][t] + hpart[2][r][t] + hpart[3][r][t];
        hp[((size_t)jc * NN + i0 + r) * CC + t] = h;
    }
}

// Kernel 3: combine the 3 j-chunk partials per row, normalize, elu.
__global__ __launch_bounds__(256) void k_comb(
    const float* __restrict__ hp,
    const float* __restrict__ Mp,
    const float* __restrict__ Lp,
    float* __restrict__ out)
{
    const int t = threadIdx.x;
    const int i = blockIdx.x;

    float m0 = Mp[i*NJC+0], m1 = Mp[i*NJC+1], m2 = Mp[i*NJC+2];
    float M  = fmaxf(fmaxf(m0, m1), m2);
    float w0 = __expf(m0 - M), w1 = __expf(m1 - M), w2 = __expf(m2 - M);
    float den = w0*Lp[i*NJC+0] + w1*Lp[i*NJC+1] + w2*Lp[i*NJC+2];
    float inv = 1.0f / den;

    float num = w0 * hp[((size_t)0*NN + i)*CC + t]
              + w1 * hp[((size_t)1*NN + i)*CC + t]
              + w2 * hp[((size_t)2*NN + i)*CC + t];
    float v = num * inv;
    out[i*CC + t] = (v > 0.f) ? v : (__expf(v) - 1.0f);
}

extern "C" void kernel_launch(void* const* d_in, const int* in_sizes, int n_in,
                              void* d_out, int out_size, void* d_ws, size_t ws_size,
                              hipStream_t stream) {
    const float* features = (const float*)d_in[0];
    const float* coords   = (const float*)d_in[1];
    // d_in[2] = adj, unused by forward
    const float* FC       = (const float*)d_in[3];
    const float* fc_w     = (const float*)d_in[4];
    const float* fc_b     = (const float*)d_in[5];
    const float* sc_w     = (const float*)d_in[6];
    const float* sc_b     = (const float*)d_in[7];
    const float* lin_w    = (const float*)d_in[8];
    const float* lin_b    = (const float*)d_in[9];
    float* out = (float*)d_out;

    float* f  = (float*)d_ws;              // N*C
    float* g  = f  + NN*CC;                // C*N
    float* D0 = g  + CC*NN;                // N
    float* D1 = D0 + NN;                   // N
    float* Mp = D1 + NN;                   // N*NJC
    float* Lp = Mp + NN*NJC;               // N*NJC
    float* hp = Lp + NN*NJC;               // NJC*N*C
    float4* ut4;
    {
        size_t off = (size_t)((char*)(hp + (size_t)NJC*NN*CC) - (char*)d_ws);
        off = (off + 15) & ~(size_t)15;
        ut4 = (float4*)((char*)d_ws + off); // (N/3)*C float4, 16B-aligned
    }

    k_prep<<<NN/TI, 768, 0, stream>>>(features, FC, fc_w, fc_b, lin_w, f, g, D0, D1, ut4);
    k_attn<<<(NN/TI)*NJC, 256, 0, stream>>>(f, g, ut4, D0, D1, coords, sc_w, sc_b,
                                            lin_w, lin_b, hp, Mp, Lp);
    k_comb<<<NN, 256, 0, stream>>>(hp, Mp, Lp, out);
}